// Round 1
// baseline (250.446 us; speedup 1.0000x reference)
//
#include <hip/hip_runtime.h>
#include <hip/hip_bf16.h>
#include <stdint.h>

#define CDIM 512
#define WDIM 2048
#define BDIM 8
#define NGRP 32

typedef unsigned short u16;
typedef __attribute__((ext_vector_type(8))) short bf16x8;
typedef __attribute__((ext_vector_type(4))) float f32x4;

__device__ __forceinline__ float bf2f(u16 u) {
  return __builtin_bit_cast(float, (uint32_t)(u) << 16);
}
__device__ __forceinline__ u16 f2bf(float f) {
  return __builtin_bit_cast(u16, __float2bfloat16(f));
}

__device__ __forceinline__ void gld_lds16(const void* g, void* l) {
  __builtin_amdgcn_global_load_lds(
      (const __attribute__((address_space(1))) uint32_t*)(uintptr_t)(g),
      (__attribute__((address_space(3))) uint32_t*)(uintptr_t)(l),
      16, 0, 0);
}

// ---------------- weight fp32 -> bf16 ----------------
__global__ __launch_bounds__(256) void cvt_weights(
    const float* __restrict__ a, const float* __restrict__ b,
    const float* __restrict__ c, const float* __restrict__ d,
    u16* __restrict__ o) {
  int i = blockIdx.x * 256 + threadIdx.x;  // 262144 elements each
  o[i]          = f2bf(a[i]);
  o[262144 + i] = f2bf(b[i]);
  o[524288 + i] = f2bf(c[i]);
  o[786432 + i] = f2bf(d[i]);
}

// ---------------- groupnorm stats: one block per (b,g) ----------------
__global__ __launch_bounds__(256) void gn_stats(const float* __restrict__ x,
                                                float* __restrict__ mr) {
  const int bg = blockIdx.x;              // b*32+g
  const float4* xp = (const float4*)(x + (size_t)bg * 16 * WDIM);
  const int n4 = 16 * WDIM / 4;           // 8192 float4
  float s = 0.f, s2 = 0.f;
  for (int i = threadIdx.x; i < n4; i += 256) {
    float4 v = xp[i];
    s += v.x + v.y + v.z + v.w;
    s2 = fmaf(v.x, v.x, s2); s2 = fmaf(v.y, v.y, s2);
    s2 = fmaf(v.z, v.z, s2); s2 = fmaf(v.w, v.w, s2);
  }
  for (int off = 32; off; off >>= 1) {
    s  += __shfl_xor(s, off, 64);
    s2 += __shfl_xor(s2, off, 64);
  }
  __shared__ float red[2][4];
  if ((threadIdx.x & 63) == 0) {
    red[0][threadIdx.x >> 6] = s;
    red[1][threadIdx.x >> 6] = s2;
  }
  __syncthreads();
  if (threadIdx.x == 0) {
    float S = red[0][0] + red[0][1] + red[0][2] + red[0][3];
    float S2 = red[1][0] + red[1][1] + red[1][2] + red[1][3];
    const float inv_n = 1.0f / (16.0f * WDIM);
    float m = S * inv_n;
    float var = S2 * inv_n - m * m;
    mr[bg * 2] = m;
    mr[bg * 2 + 1] = rsqrtf(var + 1e-6f);
  }
}

// ---------------- groupnorm apply + transpose -> hT[b][w][c] bf16 ----------------
__global__ __launch_bounds__(256) void gn_apply(
    const float* __restrict__ x, const float* __restrict__ mr,
    const float* __restrict__ gamma, const float* __restrict__ beta,
    u16* __restrict__ hT) {
  const int b = blockIdx.x >> 6;           // 8 batches
  const int w0 = (blockIdx.x & 63) * 32;   // 64 w-tiles of 32
  __shared__ u16 tile[CDIM][33];
  const float* xb = x + (size_t)b * CDIM * WDIM;
  const int c_sub = threadIdx.x >> 5;      // 0..7
  const int w_l = threadIdx.x & 31;
  for (int c0 = 0; c0 < CDIM; c0 += 8) {
    int c = c0 + c_sub;
    int g = c >> 4;
    float m = mr[(b * NGRP + g) * 2];
    float r = mr[(b * NGRP + g) * 2 + 1];
    float v = xb[(size_t)c * WDIM + w0 + w_l];
    float hn = (v - m) * r * gamma[c] + beta[c];
    tile[c][w_l] = f2bf(hn);
  }
  __syncthreads();
  #pragma unroll 4
  for (int i = 0; i < 32; i++) {
    size_t base = ((size_t)b * WDIM + w0 + i) * CDIM;
    hT[base + threadIdx.x] = tile[threadIdx.x][i];
    hT[base + 256 + threadIdx.x] = tile[256 + threadIdx.x][i];
  }
}

// ---------------- uniform TN GEMM: C[m][n] = sum_k A[m][k]*B[n][k] ----------------
// BIAS_MODE: 0 none, 1 bias[n], 2 bias[m].  SCALE: multiply (acc+bias) by scale.
// RESID: add resid[idx] (same layout as C).
template <int BIAS_MODE, int RESID, int SCALE, typename OutT>
__global__ __launch_bounds__(256) void gemm_tn(
    const u16* __restrict__ A, const u16* __restrict__ B,
    OutT* __restrict__ Cp, const float* __restrict__ bias,
    const float* __restrict__ resid, float scale, int K, int N,
    long sAb, long sBb, long sCb) {
  __shared__ u16 Asm[128 * 32];
  __shared__ u16 Bsm[128 * 32];
  const int tid = threadIdx.x;
  const int wave = tid >> 6, lane = tid & 63;
  const int wm = (wave >> 1) << 6, wn = (wave & 1) << 6;
  const size_t zc = (size_t)blockIdx.z * sCb;
  const u16* Ab = A + (size_t)blockIdx.z * sAb + (size_t)blockIdx.x * 128 * K;
  const u16* Bb = B + (size_t)blockIdx.z * sBb + (size_t)blockIdx.y * 128 * K;

  const int srow = lane >> 2;        // 0..15 within 16-row chunk
  const int skk = (lane & 3) * 8;    // k offset 0/8/16/24
  const int c0 = wave * 2;

  f32x4 acc[4][4] = {};
  const int fr = lane & 15;
  const int fk = (lane >> 4) * 8;

  for (int k0 = 0; k0 < K; k0 += 32) {
    const u16* Ak = Ab + k0;
    const u16* Bk = Bb + k0;
    #pragma unroll
    for (int j = 0; j < 2; j++) {
      int chunk = c0 + j;
      int row = chunk * 16 + srow;
      gld_lds16(Ak + (size_t)row * K + skk, Asm + chunk * 512);
      gld_lds16(Bk + (size_t)row * K + skk, Bsm + chunk * 512);
    }
    asm volatile("s_waitcnt vmcnt(0)" ::: "memory");
    __syncthreads();

    bf16x8 af[4], bfr[4];
    #pragma unroll
    for (int i = 0; i < 4; i++)
      af[i] = *(const bf16x8*)(Asm + (wm + i * 16 + fr) * 32 + fk);
    #pragma unroll
    for (int i = 0; i < 4; i++)
      bfr[i] = *(const bf16x8*)(Bsm + (wn + i * 16 + fr) * 32 + fk);
    #pragma unroll
    for (int mi = 0; mi < 4; mi++)
      #pragma unroll
      for (int ni = 0; ni < 4; ni++)
        acc[mi][ni] = __builtin_amdgcn_mfma_f32_16x16x32_bf16(
            af[mi], bfr[ni], acc[mi][ni], 0, 0, 0);
    __syncthreads();
  }

  const int row0 = blockIdx.x * 128 + wm + (lane >> 4) * 4;
  const int coln = blockIdx.y * 128 + wn + fr;
  #pragma unroll
  for (int mi = 0; mi < 4; mi++) {
    #pragma unroll
    for (int ni = 0; ni < 4; ni++) {
      int n = coln + ni * 16;
      float bn_ = (BIAS_MODE == 1) ? bias[n] : 0.0f;
      #pragma unroll
      for (int j = 0; j < 4; j++) {
        int m = row0 + mi * 16 + j;
        float v = acc[mi][ni][j];
        if (BIAS_MODE == 1) v += bn_;
        if (BIAS_MODE == 2) v += bias[m];
        if (SCALE) v *= scale;
        size_t idx = zc + (size_t)m * N + n;
        if (RESID) v += resid[idx];
        if constexpr (sizeof(OutT) == 2) {
          Cp[idx] = (OutT)f2bf(v);
        } else {
          Cp[idx] = v;
        }
      }
    }
  }
}

// ---------------- row softmax in place over bf16 scores ----------------
__global__ __launch_bounds__(256) void softmax_rows(u16* __restrict__ sc) {
  const size_t base = (size_t)blockIdx.x * WDIM;
  const int tid = threadIdx.x;
  bf16x8 raw = *(const bf16x8*)(sc + base + tid * 8);
  float v[8];
  float mx = -1e30f;
  #pragma unroll
  for (int j = 0; j < 8; j++) {
    v[j] = bf2f((u16)raw[j]);
    mx = fmaxf(mx, v[j]);
  }
  for (int off = 32; off; off >>= 1) mx = fmaxf(mx, __shfl_xor(mx, off, 64));
  __shared__ float smx[4], ssum[4];
  if ((tid & 63) == 0) smx[tid >> 6] = mx;
  __syncthreads();
  mx = fmaxf(fmaxf(smx[0], smx[1]), fmaxf(smx[2], smx[3]));
  float sum = 0.f;
  #pragma unroll
  for (int j = 0; j < 8; j++) {
    v[j] = __expf(v[j] - mx);
    sum += v[j];
  }
  for (int off = 32; off; off >>= 1) sum += __shfl_xor(sum, off, 64);
  if ((tid & 63) == 0) ssum[tid >> 6] = sum;
  __syncthreads();
  float r = 1.0f / (ssum[0] + ssum[1] + ssum[2] + ssum[3]);
  bf16x8 outv;
  #pragma unroll
  for (int j = 0; j < 8; j++) outv[j] = (short)f2bf(v[j] * r);
  *(bf16x8*)(sc + base + tid * 8) = outv;
}

extern "C" void kernel_launch(void* const* d_in, const int* in_sizes, int n_in,
                              void* d_out, int out_size, void* d_ws,
                              size_t ws_size, hipStream_t stream) {
  const float* x     = (const float*)d_in[0];
  const float* gamma = (const float*)d_in[1];
  const float* beta  = (const float*)d_in[2];
  const float* wq    = (const float*)d_in[3];
  const float* bq    = (const float*)d_in[4];
  const float* wk    = (const float*)d_in[5];
  const float* bk    = (const float*)d_in[6];
  const float* wv    = (const float*)d_in[7];
  const float* bv    = (const float*)d_in[8];
  const float* wp    = (const float*)d_in[9];
  const float* bp    = (const float*)d_in[10];
  float* out = (float*)d_out;

  char* ws = (char*)d_ws;
  u16* wq_bf = (u16*)ws;                    // 4 x 262144 bf16
  u16* wk_bf = wq_bf + 262144;
  u16* wv_bf = wk_bf + 262144;
  u16* wp_bf = wv_bf + 262144;
  float* mr = (float*)(ws + 4 * 524288);    // 512 floats (mean,rstd)
  u16* hT = (u16*)(ws + 4 * 524288 + 4096); // 8*2048*512
  u16* qT = hT + 8388608;
  u16* kT = qT + 8388608;
  u16* vB = kT + 8388608;
  u16* oT = vB + 8388608;
  u16* sc = oT + 8388608;                   // 8*2048*2048

  const long sWC = (long)WDIM * CDIM;       // 1048576
  const long sCW = (long)CDIM * WDIM;
  const long sWW = (long)WDIM * WDIM;       // 4194304

  cvt_weights<<<1024, 256, 0, stream>>>(wq, wk, wv, wp, wq_bf);
  gn_stats<<<BDIM * NGRP, 256, 0, stream>>>(x, mr);
  gn_apply<<<BDIM * 64, 256, 0, stream>>>(x, mr, gamma, beta, hT);

  const float scale = 0.04419417382415922f;  // 512^-0.5

  // qT[b][w][c] = (hT . Wq^T + bq) * scale
  gemm_tn<1, 0, 1, u16><<<dim3(16, 4, 8), 256, 0, stream>>>(
      hT, wq_bf, qT, bq, nullptr, scale, 512, 512, sWC, 0, sWC);
  // kT[b][w][c] = hT . Wk^T + bk
  gemm_tn<1, 0, 0, u16><<<dim3(16, 4, 8), 256, 0, stream>>>(
      hT, wk_bf, kT, bk, nullptr, 1.f, 512, 512, sWC, 0, sWC);
  // v[b][c][w] = Wv . h + bv
  gemm_tn<2, 0, 0, u16><<<dim3(4, 16, 8), 256, 0, stream>>>(
      wv_bf, hT, vB, bv, nullptr, 1.f, 512, 2048, 0, sWC, sCW);
  // scores[b][i][j] = qT . kT^T
  gemm_tn<0, 0, 0, u16><<<dim3(16, 16, 8), 256, 0, stream>>>(
      qT, kT, sc, nullptr, nullptr, 1.f, 512, 2048, sWC, sWC, sWW);
  // softmax rows
  softmax_rows<<<BDIM * WDIM, 256, 0, stream>>>(sc);
  // oT[b][i][c] = att . v^T
  gemm_tn<0, 0, 0, u16><<<dim3(16, 4, 8), 256, 0, stream>>>(
      sc, vB, oT, nullptr, nullptr, 1.f, 2048, 512, sWW, sCW, sWC);
  // out[b][c][i] = wp . o + bp + x
  gemm_tn<2, 1, 0, float><<<dim3(4, 16, 8), 256, 0, stream>>>(
      wp_bf, oT, out, bp, x, 1.f, 512, 2048, 0, sWC, sCW);
}

// Round 2
// 215.657 us; speedup vs baseline: 1.1613x; 1.1613x over previous
//
#include <hip/hip_runtime.h>
#include <hip/hip_bf16.h>
#include <stdint.h>

#define CDIM 512
#define WDIM 2048
#define BDIM 8
#define NGRP 32

typedef unsigned short u16;
typedef __attribute__((ext_vector_type(8))) short bf16x8;
typedef __attribute__((ext_vector_type(4))) float f32x4;

__device__ __forceinline__ float bf2f(u16 u) {
  return __builtin_bit_cast(float, (uint32_t)(u) << 16);
}
__device__ __forceinline__ u16 f2bf(float f) {
  return __builtin_bit_cast(u16, __float2bfloat16(f));
}

__device__ __forceinline__ void gld_lds16(const void* g, void* l) {
  __builtin_amdgcn_global_load_lds(
      (const __attribute__((address_space(1))) uint32_t*)(uintptr_t)(g),
      (__attribute__((address_space(3))) uint32_t*)(uintptr_t)(l),
      16, 0, 0);
}

// ---------------- weight fp32 -> bf16 ----------------
__global__ __launch_bounds__(256) void cvt_weights(
    const float* __restrict__ a, const float* __restrict__ b,
    const float* __restrict__ c, const float* __restrict__ d,
    u16* __restrict__ o) {
  int i = blockIdx.x * 256 + threadIdx.x;  // 262144 elements each
  o[i]          = f2bf(a[i]);
  o[262144 + i] = f2bf(b[i]);
  o[524288 + i] = f2bf(c[i]);
  o[786432 + i] = f2bf(d[i]);
}

// ---------------- groupnorm stats: one block per (b,g) ----------------
__global__ __launch_bounds__(256) void gn_stats(const float* __restrict__ x,
                                                float* __restrict__ mr) {
  const int bg = blockIdx.x;              // b*32+g
  const float4* xp = (const float4*)(x + (size_t)bg * 16 * WDIM);
  const int n4 = 16 * WDIM / 4;           // 8192 float4
  float s = 0.f, s2 = 0.f;
  for (int i = threadIdx.x; i < n4; i += 256) {
    float4 v = xp[i];
    s += v.x + v.y + v.z + v.w;
    s2 = fmaf(v.x, v.x, s2); s2 = fmaf(v.y, v.y, s2);
    s2 = fmaf(v.z, v.z, s2); s2 = fmaf(v.w, v.w, s2);
  }
  for (int off = 32; off; off >>= 1) {
    s  += __shfl_xor(s, off, 64);
    s2 += __shfl_xor(s2, off, 64);
  }
  __shared__ float red[2][4];
  if ((threadIdx.x & 63) == 0) {
    red[0][threadIdx.x >> 6] = s;
    red[1][threadIdx.x >> 6] = s2;
  }
  __syncthreads();
  if (threadIdx.x == 0) {
    float S = red[0][0] + red[0][1] + red[0][2] + red[0][3];
    float S2 = red[1][0] + red[1][1] + red[1][2] + red[1][3];
    const float inv_n = 1.0f / (16.0f * WDIM);
    float m = S * inv_n;
    float var = S2 * inv_n - m * m;
    mr[bg * 2] = m;
    mr[bg * 2 + 1] = rsqrtf(var + 1e-6f);
  }
}

// ---------------- groupnorm apply + transpose -> hT[b][w][c] bf16 ----------------
__global__ __launch_bounds__(256) void gn_apply(
    const float* __restrict__ x, const float* __restrict__ mr,
    const float* __restrict__ gamma, const float* __restrict__ beta,
    u16* __restrict__ hT) {
  const int b = blockIdx.x >> 6;           // 8 batches
  const int w0 = (blockIdx.x & 63) * 32;   // 64 w-tiles of 32
  __shared__ u16 tile[CDIM][33];
  const float* xb = x + (size_t)b * CDIM * WDIM;
  const int c_sub = threadIdx.x >> 5;      // 0..7
  const int w_l = threadIdx.x & 31;
  for (int c0 = 0; c0 < CDIM; c0 += 8) {
    int c = c0 + c_sub;
    int g = c >> 4;
    float m = mr[(b * NGRP + g) * 2];
    float r = mr[(b * NGRP + g) * 2 + 1];
    float v = xb[(size_t)c * WDIM + w0 + w_l];
    float hn = (v - m) * r * gamma[c] + beta[c];
    tile[c][w_l] = f2bf(hn);
  }
  __syncthreads();
  #pragma unroll 4
  for (int i = 0; i < 32; i++) {
    size_t base = ((size_t)b * WDIM + w0 + i) * CDIM;
    hT[base + threadIdx.x] = tile[threadIdx.x][i];
    hT[base + 256 + threadIdx.x] = tile[256 + threadIdx.x][i];
  }
}

// ---------------- uniform TN GEMM: C[m][n] = sum_k A[m][k]*B[n][k] ----------------
// 3-buffer ring, 2-tile-deep prefetch, counted vmcnt, raw s_barrier (1/iter).
// BIAS_MODE: 0 none, 1 bias[n], 2 bias[m].  SCALE: multiply (acc+bias) by scale.
// RESID: add resid[idx] (same layout as C).
template <int BIAS_MODE, int RESID, int SCALE, typename OutT>
__global__ __launch_bounds__(256) void gemm_tn(
    const u16* __restrict__ A, const u16* __restrict__ B,
    OutT* __restrict__ Cp, const float* __restrict__ bias,
    const float* __restrict__ resid, float scale, int K, int N,
    int lda, int ldb, long sAb, long sBb, long sCb) {
  __shared__ u16 Asm[3 * 4096];   // 3 bufs x [128][32]
  __shared__ u16 Bsm[3 * 4096];
  const int tid = threadIdx.x;
  const int wave = tid >> 6, lane = tid & 63;
  const int wm = (wave >> 1) << 6, wn = (wave & 1) << 6;
  const size_t zc = (size_t)blockIdx.z * sCb;
  const u16* Ab = A + (size_t)blockIdx.z * sAb + (size_t)blockIdx.x * 128 * lda;
  const u16* Bb = B + (size_t)blockIdx.z * sBb + (size_t)blockIdx.y * 128 * ldb;

  const int srow = lane >> 2;        // 0..15 within 16-row chunk
  const int skk = (lane & 3) * 8;    // k offset 0/8/16/24 elements
  const int c0 = wave * 2;

  f32x4 acc[4][4] = {};
  const int fr = lane & 15;
  const int fk = (lane >> 4) * 8;

  auto stage = [&](int buf, int t) {
    const u16* Ak = Ab + t * 32;
    const u16* Bk = Bb + t * 32;
    u16* As = Asm + buf * 4096;
    u16* Bs = Bsm + buf * 4096;
    #pragma unroll
    for (int j = 0; j < 2; j++) {
      int chunk = c0 + j;
      int row = chunk * 16 + srow;
      gld_lds16(Ak + (size_t)row * lda + skk, As + chunk * 512);
      gld_lds16(Bk + (size_t)row * ldb + skk, Bs + chunk * 512);
    }
  };

  const int nt = K >> 5;             // >= 16 for all our shapes
  stage(0, 0);
  stage(1, 1);
  asm volatile("s_waitcnt vmcnt(4)" ::: "memory");   // tile 0 landed (own)
  __builtin_amdgcn_s_barrier();                      // all waves' tile 0 landed
  asm volatile("" ::: "memory");

  for (int t = 0; t < nt; ++t) {
    const int cur = t % 3;
    const u16* As = Asm + cur * 4096;
    const u16* Bs = Bsm + cur * 4096;
    bf16x8 af[4], bfr[4];
    #pragma unroll
    for (int i = 0; i < 4; i++)
      af[i] = *(const bf16x8*)(As + (wm + i * 16 + fr) * 32 + fk);
    #pragma unroll
    for (int i = 0; i < 4; i++)
      bfr[i] = *(const bf16x8*)(Bs + (wn + i * 16 + fr) * 32 + fk);

    if (t + 2 < nt) stage((t + 2) % 3, t + 2);

    __builtin_amdgcn_s_setprio(1);
    #pragma unroll
    for (int mi = 0; mi < 4; mi++)
      #pragma unroll
      for (int ni = 0; ni < 4; ni++)
        acc[mi][ni] = __builtin_amdgcn_mfma_f32_16x16x32_bf16(
            af[mi], bfr[ni], acc[mi][ni], 0, 0, 0);
    __builtin_amdgcn_s_setprio(0);

    if (t + 1 < nt) {
      // outstanding: tile t+1 (4 loads) [+ tile t+2 (4) if staged].
      // wait until tile t+1 landed; keep t+2 in flight across the barrier.
      if (t + 2 < nt)
        asm volatile("s_waitcnt vmcnt(4)" ::: "memory");
      else
        asm volatile("s_waitcnt vmcnt(0)" ::: "memory");
      __builtin_amdgcn_s_barrier();
      asm volatile("" ::: "memory");
    }
  }

  const int row0 = blockIdx.x * 128 + wm + (lane >> 4) * 4;
  const int coln = blockIdx.y * 128 + wn + fr;
  #pragma unroll
  for (int mi = 0; mi < 4; mi++) {
    #pragma unroll
    for (int ni = 0; ni < 4; ni++) {
      int n = coln + ni * 16;
      float bn_ = (BIAS_MODE == 1) ? bias[n] : 0.0f;
      #pragma unroll
      for (int j = 0; j < 4; j++) {
        int m = row0 + mi * 16 + j;
        float v = acc[mi][ni][j];
        if (BIAS_MODE == 1) v += bn_;
        if (BIAS_MODE == 2) v += bias[m];
        if (SCALE) v *= scale;
        size_t idx = zc + (size_t)m * N + n;
        if (RESID) v += resid[idx];
        if constexpr (sizeof(OutT) == 2) {
          Cp[idx] = (OutT)f2bf(v);
        } else {
          Cp[idx] = v;
        }
      }
    }
  }
}

// ---------------- row softmax in place over bf16 scores ----------------
__global__ __launch_bounds__(256) void softmax_rows(u16* __restrict__ sc) {
  const size_t base = (size_t)blockIdx.x * WDIM;
  const int tid = threadIdx.x;
  bf16x8 raw = *(const bf16x8*)(sc + base + tid * 8);
  float v[8];
  float mx = -1e30f;
  #pragma unroll
  for (int j = 0; j < 8; j++) {
    v[j] = bf2f((u16)raw[j]);
    mx = fmaxf(mx, v[j]);
  }
  for (int off = 32; off; off >>= 1) mx = fmaxf(mx, __shfl_xor(mx, off, 64));
  __shared__ float smx[4], ssum[4];
  if ((tid & 63) == 0) smx[tid >> 6] = mx;
  __syncthreads();
  mx = fmaxf(fmaxf(smx[0], smx[1]), fmaxf(smx[2], smx[3]));
  float sum = 0.f;
  #pragma unroll
  for (int j = 0; j < 8; j++) {
    v[j] = __expf(v[j] - mx);
    sum += v[j];
  }
  for (int off = 32; off; off >>= 1) sum += __shfl_xor(sum, off, 64);
  if ((tid & 63) == 0) ssum[tid >> 6] = sum;
  __syncthreads();
  float r = 1.0f / (ssum[0] + ssum[1] + ssum[2] + ssum[3]);
  bf16x8 outv;
  #pragma unroll
  for (int j = 0; j < 8; j++) outv[j] = (short)f2bf(v[j] * r);
  *(bf16x8*)(sc + base + tid * 8) = outv;
}

extern "C" void kernel_launch(void* const* d_in, const int* in_sizes, int n_in,
                              void* d_out, int out_size, void* d_ws,
                              size_t ws_size, hipStream_t stream) {
  const float* x     = (const float*)d_in[0];
  const float* gamma = (const float*)d_in[1];
  const float* beta  = (const float*)d_in[2];
  const float* wq    = (const float*)d_in[3];
  const float* bq    = (const float*)d_in[4];
  const float* wk    = (const float*)d_in[5];
  const float* bk    = (const float*)d_in[6];
  const float* wv    = (const float*)d_in[7];
  const float* bv    = (const float*)d_in[8];
  const float* wp    = (const float*)d_in[9];
  const float* bp    = (const float*)d_in[10];
  float* out = (float*)d_out;

  char* ws = (char*)d_ws;
  u16* wq_bf = (u16*)ws;                    // 4 x 262144 bf16
  u16* wk_bf = wq_bf + 262144;
  u16* wv_bf = wk_bf + 262144;
  u16* wp_bf = wv_bf + 262144;
  float* mr = (float*)(ws + 4 * 524288);    // 512 floats (mean,rstd)
  u16* hT = (u16*)(ws + 4 * 524288 + 4096); // 8*2048*512
  u16* qT = hT + 8388608;
  u16* kT = qT + 8388608;
  u16* vB = kT + 8388608;
  u16* oT = vB + 8388608;
  u16* sc = oT + 8388608;                   // 8*2048*2048

  const long sWC = (long)WDIM * CDIM;       // 1048576
  const long sCW = (long)CDIM * WDIM;
  const long sWW = (long)WDIM * WDIM;       // 4194304

  cvt_weights<<<1024, 256, 0, stream>>>(wq, wk, wv, wp, wq_bf);
  gn_stats<<<BDIM * NGRP, 256, 0, stream>>>(x, mr);
  gn_apply<<<BDIM * 64, 256, 0, stream>>>(x, mr, gamma, beta, hT);

  const float scale = 0.04419417382415922f;  // 512^-0.5

  // qT[b][w][c] = (hT . Wq^T + bq) * scale
  gemm_tn<1, 0, 1, u16><<<dim3(16, 4, 8), 256, 0, stream>>>(
      hT, wq_bf, qT, bq, nullptr, scale, 512, 512, 512, 512, sWC, 0, sWC);
  // kT[b][w][c] = hT . Wk^T + bk
  gemm_tn<1, 0, 0, u16><<<dim3(16, 4, 8), 256, 0, stream>>>(
      hT, wk_bf, kT, bk, nullptr, 1.f, 512, 512, 512, 512, sWC, 0, sWC);
  // v[b][c][w] = Wv . h + bv
  gemm_tn<2, 0, 0, u16><<<dim3(4, 16, 8), 256, 0, stream>>>(
      wv_bf, hT, vB, bv, nullptr, 1.f, 512, 2048, 512, 512, 0, sWC, sCW);
  // scores[b][i][j] = qT . kT^T
  gemm_tn<0, 0, 0, u16><<<dim3(16, 16, 8), 256, 0, stream>>>(
      qT, kT, sc, nullptr, nullptr, 1.f, 512, 2048, 512, 512, sWC, sWC, sWW);
  // softmax rows
  softmax_rows<<<BDIM * WDIM, 256, 0, stream>>>(sc);
  // oT[b][i][c] = att . v^T
  gemm_tn<0, 0, 0, u16><<<dim3(16, 4, 8), 256, 0, stream>>>(
      sc, vB, oT, nullptr, nullptr, 1.f, 2048, 512, 2048, 2048, sWW, sCW, sWC);
  // out[b][c][i] = wp . o + bp + x
  gemm_tn<2, 1, 0, float><<<dim3(4, 16, 8), 256, 0, stream>>>(
      wp_bf, oT, out, bp, x, 1.f, 512, 2048, 512, 512, 0, sWC, sCW);
}

// Round 3
// 211.930 us; speedup vs baseline: 1.1817x; 1.0176x over previous
//
#include <hip/hip_runtime.h>
#include <hip/hip_bf16.h>
#include <stdint.h>

#define CDIM 512
#define WDIM 2048
#define BDIM 8
#define NGRP 32

typedef unsigned short u16;
typedef __attribute__((ext_vector_type(8))) short bf16x8;
typedef __attribute__((ext_vector_type(4))) float f32x4;

__device__ __forceinline__ float bf2f(u16 u) {
  return __builtin_bit_cast(float, (uint32_t)(u) << 16);
}
__device__ __forceinline__ u16 f2bf(float f) {
  return __builtin_bit_cast(u16, __float2bfloat16(f));
}

__device__ __forceinline__ void gld_lds16(const void* g, void* l) {
  __builtin_amdgcn_global_load_lds(
      (const __attribute__((address_space(1))) uint32_t*)(uintptr_t)(g),
      (__attribute__((address_space(3))) uint32_t*)(uintptr_t)(l),
      16, 0, 0);
}

// ---------------- weight fp32 -> bf16 ----------------
__global__ __launch_bounds__(256) void cvt_weights(
    const float* __restrict__ a, const float* __restrict__ b,
    const float* __restrict__ c, const float* __restrict__ d,
    u16* __restrict__ o) {
  int i = blockIdx.x * 256 + threadIdx.x;  // 262144 elements each
  o[i]          = f2bf(a[i]);
  o[262144 + i] = f2bf(b[i]);
  o[524288 + i] = f2bf(c[i]);
  o[786432 + i] = f2bf(d[i]);
}

// ---------------- groupnorm stats: one block per (b,g) ----------------
__global__ __launch_bounds__(256) void gn_stats(const float* __restrict__ x,
                                                float* __restrict__ mr) {
  const int bg = blockIdx.x;              // b*32+g
  const float4* xp = (const float4*)(x + (size_t)bg * 16 * WDIM);
  const int n4 = 16 * WDIM / 4;           // 8192 float4
  float s = 0.f, s2 = 0.f;
  for (int i = threadIdx.x; i < n4; i += 256) {
    float4 v = xp[i];
    s += v.x + v.y + v.z + v.w;
    s2 = fmaf(v.x, v.x, s2); s2 = fmaf(v.y, v.y, s2);
    s2 = fmaf(v.z, v.z, s2); s2 = fmaf(v.w, v.w, s2);
  }
  for (int off = 32; off; off >>= 1) {
    s  += __shfl_xor(s, off, 64);
    s2 += __shfl_xor(s2, off, 64);
  }
  __shared__ float red[2][4];
  if ((threadIdx.x & 63) == 0) {
    red[0][threadIdx.x >> 6] = s;
    red[1][threadIdx.x >> 6] = s2;
  }
  __syncthreads();
  if (threadIdx.x == 0) {
    float S = red[0][0] + red[0][1] + red[0][2] + red[0][3];
    float S2 = red[1][0] + red[1][1] + red[1][2] + red[1][3];
    const float inv_n = 1.0f / (16.0f * WDIM);
    float m = S * inv_n;
    float var = S2 * inv_n - m * m;
    mr[bg * 2] = m;
    mr[bg * 2 + 1] = rsqrtf(var + 1e-6f);
  }
}

// ---------------- groupnorm apply + transpose -> hT[b][w][c] bf16 ----------------
__global__ __launch_bounds__(256) void gn_apply(
    const float* __restrict__ x, const float* __restrict__ mr,
    const float* __restrict__ gamma, const float* __restrict__ beta,
    u16* __restrict__ hT) {
  const int b = blockIdx.x >> 6;           // 8 batches
  const int w0 = (blockIdx.x & 63) * 32;   // 64 w-tiles of 32
  __shared__ u16 tile[CDIM][33];
  const float* xb = x + (size_t)b * CDIM * WDIM;
  const int c_sub = threadIdx.x >> 5;      // 0..7
  const int w_l = threadIdx.x & 31;
  for (int c0 = 0; c0 < CDIM; c0 += 8) {
    int c = c0 + c_sub;
    int g = c >> 4;
    float m = mr[(b * NGRP + g) * 2];
    float r = mr[(b * NGRP + g) * 2 + 1];
    float v = xb[(size_t)c * WDIM + w0 + w_l];
    float hn = (v - m) * r * gamma[c] + beta[c];
    tile[c][w_l] = f2bf(hn);
  }
  __syncthreads();
  #pragma unroll 4
  for (int i = 0; i < 32; i++) {
    size_t base = ((size_t)b * WDIM + w0 + i) * CDIM;
    hT[base + threadIdx.x] = tile[threadIdx.x][i];
    hT[base + 256 + threadIdx.x] = tile[256 + threadIdx.x][i];
  }
}

// ---------------- big TN GEMM: C[m][n] = sum_k A[m][k]*B[n][k] ----------------
// BM=256, BN=128, BK=64. 512 threads = 8 waves (2x4). Ring-3 LDS (144KB),
// prefetch 2 K-tiles ahead, counted vmcnt(6), 1 barrier per K-tile.
// XOR chunk-swizzle (slot ^= row&7) applied to BOTH the pre-swizzled global
// staging source and the ds_read address (LDS stays linear for gld_lds).
// BIAS_MODE: 0 none, 1 bias[n], 2 bias[m], 3 split-n (bq/bk at n<512/>=512).
template <int BIAS_MODE, int RESID, int SCALE, typename OutT>
__global__ __launch_bounds__(512, 2) void gemm_tn(
    const u16* __restrict__ A, const u16* __restrict__ B,
    OutT* __restrict__ Cp, const float* __restrict__ bias,
    const float* __restrict__ bias2, const float* __restrict__ resid,
    float scale, int K, int N, int lda, int ldb,
    long sAb, long sBb, long sCb) {
  extern __shared__ char smem[];           // 3 * (32KB A + 16KB B) = 147456
  const int tid = threadIdx.x;
  const int wave = tid >> 6, lane = tid & 63;
  const int wr = wave >> 2, wc = wave & 3;   // 2 x 4 wave grid
  const int fr = lane & 15, kg = lane >> 4;  // frag row, k-group
  const size_t zc = (size_t)blockIdx.z * sCb;
  const u16* Ab = A + (size_t)blockIdx.z * sAb + (size_t)blockIdx.x * 256 * lda;
  const u16* Bb = B + (size_t)blockIdx.z * sBb + (size_t)blockIdx.y * 128 * ldb;

  f32x4 acc[8][2] = {};

  auto stage = [&](int buf, int tk) {
    char* base = smem + buf * 49152;
    u16* As = (u16*)base;
    u16* Bs = (u16*)(base + 32768);
    const u16* Ag = Ab + tk * 64;
    const u16* Bg = Bb + tk * 64;
    #pragma unroll
    for (int j = 0; j < 4; ++j) {          // A: 256x64 = 2048 16B chunks
      int pc = j * 512 + tid;
      int row = pc >> 3;
      int ls = (pc & 7) ^ (row & 7);       // pre-swizzled source slot
      gld_lds16(Ag + (size_t)row * lda + ls * 8, As + pc * 8);
    }
    #pragma unroll
    for (int j = 0; j < 2; ++j) {          // B: 128x64 = 1024 chunks
      int pc = j * 512 + tid;
      int row = pc >> 3;
      int ls = (pc & 7) ^ (row & 7);
      gld_lds16(Bg + (size_t)row * ldb + ls * 8, Bs + pc * 8);
    }
  };

  const int nt = K >> 6;                   // K-tiles of 64 (>= 8 always here)
  stage(0, 0);
  stage(1, 1);
  asm volatile("s_waitcnt vmcnt(6)" ::: "memory");   // tile 0 landed
  __builtin_amdgcn_s_barrier();

  for (int t = 0; t < nt; ++t) {
    const int buf = t % 3;
    const char* base = smem + buf * 49152;
    const char* As = base;
    const char* Bs = base + 32768;

    if (t + 2 < nt) stage((t + 2) % 3, t + 2);   // into buffer freed at t-1

    bf16x8 af[8][2], bfv[2][2];
    #pragma unroll
    for (int ks = 0; ks < 2; ++ks) {
      const int kc = ks * 4 + kg;
      #pragma unroll
      for (int mi = 0; mi < 8; ++mi) {
        int row = wr * 128 + mi * 16 + fr;
        af[mi][ks] = *(const bf16x8*)(As + row * 128 + ((kc ^ (row & 7)) << 4));
      }
      #pragma unroll
      for (int ni = 0; ni < 2; ++ni) {
        int row = wc * 32 + ni * 16 + fr;
        bfv[ni][ks] = *(const bf16x8*)(Bs + row * 128 + ((kc ^ (row & 7)) << 4));
      }
    }

    __builtin_amdgcn_s_setprio(1);
    #pragma unroll
    for (int ks = 0; ks < 2; ++ks)
      #pragma unroll
      for (int mi = 0; mi < 8; ++mi)
        #pragma unroll
        for (int ni = 0; ni < 2; ++ni)
          acc[mi][ni] = __builtin_amdgcn_mfma_f32_16x16x32_bf16(
              af[mi][ks], bfv[ni][ks], acc[mi][ni], 0, 0, 0);
    __builtin_amdgcn_s_setprio(0);

    if (t + 1 < nt) {
      // drain own ds_reads (so next iter's staging can't race them) and
      // ensure tile t+1 landed; keep tile t+2's 6 loads in flight.
      if (t + 2 < nt)
        asm volatile("s_waitcnt vmcnt(6) lgkmcnt(0)" ::: "memory");
      else
        asm volatile("s_waitcnt vmcnt(0) lgkmcnt(0)" ::: "memory");
      __builtin_amdgcn_s_barrier();
    }
  }

  const int row0 = blockIdx.x * 256 + wr * 128 + (lane >> 4) * 4;
  const int coln = blockIdx.y * 128 + wc * 32 + fr;
  #pragma unroll
  for (int mi = 0; mi < 8; ++mi) {
    #pragma unroll
    for (int ni = 0; ni < 2; ++ni) {
      int n = coln + ni * 16;
      float badd = 0.0f;
      if (BIAS_MODE == 1) badd = bias[n];
      if (BIAS_MODE == 3) badd = (n < 512) ? bias[n] : bias2[n - 512];
      #pragma unroll
      for (int j = 0; j < 4; ++j) {
        int m = row0 + mi * 16 + j;
        float v = acc[mi][ni][j];
        if (BIAS_MODE == 2) v += bias[m]; else v += badd;
        if (SCALE) v *= scale;
        size_t idx = zc + (size_t)m * N + n;
        if (RESID) v += resid[idx];
        if constexpr (sizeof(OutT) == 2) {
          Cp[idx] = (OutT)f2bf(v);
        } else {
          Cp[idx] = v;
        }
      }
    }
  }
}

// ---------------- row softmax in place over bf16 scores ----------------
__global__ __launch_bounds__(256) void softmax_rows(u16* __restrict__ sc) {
  const size_t base = (size_t)blockIdx.x * WDIM;
  const int tid = threadIdx.x;
  bf16x8 raw = *(const bf16x8*)(sc + base + tid * 8);
  float v[8];
  float mx = -1e30f;
  #pragma unroll
  for (int j = 0; j < 8; j++) {
    v[j] = bf2f((u16)raw[j]);
    mx = fmaxf(mx, v[j]);
  }
  for (int off = 32; off; off >>= 1) mx = fmaxf(mx, __shfl_xor(mx, off, 64));
  __shared__ float smx[4], ssum[4];
  if ((tid & 63) == 0) smx[tid >> 6] = mx;
  __syncthreads();
  mx = fmaxf(fmaxf(smx[0], smx[1]), fmaxf(smx[2], smx[3]));
  float sum = 0.f;
  #pragma unroll
  for (int j = 0; j < 8; j++) {
    v[j] = __expf(v[j] - mx);
    sum += v[j];
  }
  for (int off = 32; off; off >>= 1) sum += __shfl_xor(sum, off, 64);
  if ((tid & 63) == 0) ssum[tid >> 6] = sum;
  __syncthreads();
  float r = 1.0f / (ssum[0] + ssum[1] + ssum[2] + ssum[3]);
  bf16x8 outv;
  #pragma unroll
  for (int j = 0; j < 8; j++) outv[j] = (short)f2bf(v[j] * r);
  *(bf16x8*)(sc + base + tid * 8) = outv;
}

extern "C" void kernel_launch(void* const* d_in, const int* in_sizes, int n_in,
                              void* d_out, int out_size, void* d_ws,
                              size_t ws_size, hipStream_t stream) {
  const float* x     = (const float*)d_in[0];
  const float* gamma = (const float*)d_in[1];
  const float* beta  = (const float*)d_in[2];
  const float* wq    = (const float*)d_in[3];
  const float* bq    = (const float*)d_in[4];
  const float* wk    = (const float*)d_in[5];
  const float* bk    = (const float*)d_in[6];
  const float* wv    = (const float*)d_in[7];
  const float* bv    = (const float*)d_in[8];
  const float* wp    = (const float*)d_in[9];
  const float* bp    = (const float*)d_in[10];
  float* out = (float*)d_out;

  char* ws = (char*)d_ws;
  u16* wq_bf = (u16*)ws;                    // wq,wk contiguous => combined B
  u16* wv_bf = wq_bf + 524288;
  u16* wp_bf = wv_bf + 262144;
  float* mr = (float*)(ws + 4 * 524288);    // 512 floats (mean,rstd)
  u16* hT = (u16*)(ws + 4 * 524288 + 4096); // 8*2048*512
  u16* qk = hT + 8388608;                   // 8*2048*1024 (q | k)
  u16* vB = qk + 16777216;                  // 8*512*2048
  u16* oT = vB + 8388608;                   // 8*2048*512
  u16* sc = oT + 8388608;                   // 8*2048*2048

  const long sWC = (long)WDIM * CDIM;       // 1048576
  const long sCW = (long)CDIM * WDIM;
  const long sW1024 = (long)WDIM * 1024;
  const long sWW = (long)WDIM * WDIM;       // 4194304

  const int SMEM = 147456;
  (void)hipFuncSetAttribute((const void*)&gemm_tn<3, 0, 0, u16>,
      hipFuncAttributeMaxDynamicSharedMemorySize, SMEM);
  (void)hipFuncSetAttribute((const void*)&gemm_tn<2, 0, 0, u16>,
      hipFuncAttributeMaxDynamicSharedMemorySize, SMEM);
  (void)hipFuncSetAttribute((const void*)&gemm_tn<0, 0, 1, u16>,
      hipFuncAttributeMaxDynamicSharedMemorySize, SMEM);
  (void)hipFuncSetAttribute((const void*)&gemm_tn<0, 0, 0, u16>,
      hipFuncAttributeMaxDynamicSharedMemorySize, SMEM);
  (void)hipFuncSetAttribute((const void*)&gemm_tn<2, 1, 0, float>,
      hipFuncAttributeMaxDynamicSharedMemorySize, SMEM);

  cvt_weights<<<1024, 256, 0, stream>>>(wq, wk, wv, wp, wq_bf);
  gn_stats<<<BDIM * NGRP, 256, 0, stream>>>(x, mr);
  gn_apply<<<BDIM * 64, 256, 0, stream>>>(x, mr, gamma, beta, hT);

  const float scale = 0.04419417382415922f;  // 512^-0.5

  // qk[b][w][0:512]=h.Wq^T+bq ; [512:1024]=h.Wk^T+bk
  gemm_tn<3, 0, 0, u16><<<dim3(8, 8, 8), 512, SMEM, stream>>>(
      hT, wq_bf, qk, bq, bk, nullptr, 1.f, 512, 1024, 512, 512,
      sWC, 0, sW1024);
  // v[b][c][w] = Wv . h + bv
  gemm_tn<2, 0, 0, u16><<<dim3(2, 16, 8), 512, SMEM, stream>>>(
      wv_bf, hT, vB, bv, nullptr, nullptr, 1.f, 512, 2048, 512, 512,
      0, sWC, sCW);
  // scores[b][i][j] = (q . k) * c^-0.5
  gemm_tn<0, 0, 1, u16><<<dim3(8, 16, 8), 512, SMEM, stream>>>(
      qk, qk + 512, sc, nullptr, nullptr, nullptr, scale, 512, 2048,
      1024, 1024, sW1024, sW1024, sWW);
  // softmax rows
  softmax_rows<<<BDIM * WDIM, 256, 0, stream>>>(sc);
  // oT[b][i][c] = att . v^T
  gemm_tn<0, 0, 0, u16><<<dim3(8, 4, 8), 512, SMEM, stream>>>(
      sc, vB, oT, nullptr, nullptr, nullptr, 1.f, 2048, 512, 2048, 2048,
      sWW, sCW, sWC);
  // out[b][c][i] = wp . o + bp + x
  gemm_tn<2, 1, 0, float><<<dim3(2, 16, 8), 512, SMEM, stream>>>(
      wp_bf, oT, out, bp, nullptr, x, 1.f, 512, 2048, 512, 512,
      0, sWC, sCW);
}

// Round 4
// 207.766 us; speedup vs baseline: 1.2054x; 1.0200x over previous
//
#include <hip/hip_runtime.h>
#include <hip/hip_bf16.h>
#include <stdint.h>

#define CDIM 512
#define WDIM 2048
#define BDIM 8
#define NGRP 32

typedef unsigned short u16;
typedef __attribute__((ext_vector_type(8))) short bf16x8;
typedef __attribute__((ext_vector_type(4))) float f32x4;

__device__ __forceinline__ float bf2f(u16 u) {
  return __builtin_bit_cast(float, (uint32_t)(u) << 16);
}
__device__ __forceinline__ u16 f2bf(float f) {
  return __builtin_bit_cast(u16, __float2bfloat16(f));
}

__device__ __forceinline__ void gld_lds16(const void* g, void* l) {
  __builtin_amdgcn_global_load_lds(
      (const __attribute__((address_space(1))) uint32_t*)(uintptr_t)(g),
      (__attribute__((address_space(3))) uint32_t*)(uintptr_t)(l),
      16, 0, 0);
}

// ---------------- weight fp32 -> bf16 ----------------
__global__ __launch_bounds__(256) void cvt_weights(
    const float* __restrict__ a, const float* __restrict__ b,
    const float* __restrict__ c, const float* __restrict__ d,
    u16* __restrict__ o) {
  int i = blockIdx.x * 256 + threadIdx.x;  // 262144 elements each
  o[i]          = f2bf(a[i]);
  o[262144 + i] = f2bf(b[i]);
  o[524288 + i] = f2bf(c[i]);
  o[786432 + i] = f2bf(d[i]);
}

// ---------------- groupnorm stats: one block per (b,g) ----------------
__global__ __launch_bounds__(256) void gn_stats(const float* __restrict__ x,
                                                float* __restrict__ mr) {
  const int bg = blockIdx.x;              // b*32+g
  const float4* xp = (const float4*)(x + (size_t)bg * 16 * WDIM);
  const int n4 = 16 * WDIM / 4;           // 8192 float4
  float s = 0.f, s2 = 0.f;
  for (int i = threadIdx.x; i < n4; i += 256) {
    float4 v = xp[i];
    s += v.x + v.y + v.z + v.w;
    s2 = fmaf(v.x, v.x, s2); s2 = fmaf(v.y, v.y, s2);
    s2 = fmaf(v.z, v.z, s2); s2 = fmaf(v.w, v.w, s2);
  }
  for (int off = 32; off; off >>= 1) {
    s  += __shfl_xor(s, off, 64);
    s2 += __shfl_xor(s2, off, 64);
  }
  __shared__ float red[2][4];
  if ((threadIdx.x & 63) == 0) {
    red[0][threadIdx.x >> 6] = s;
    red[1][threadIdx.x >> 6] = s2;
  }
  __syncthreads();
  if (threadIdx.x == 0) {
    float S = red[0][0] + red[0][1] + red[0][2] + red[0][3];
    float S2 = red[1][0] + red[1][1] + red[1][2] + red[1][3];
    const float inv_n = 1.0f / (16.0f * WDIM);
    float m = S * inv_n;
    float var = S2 * inv_n - m * m;
    mr[bg * 2] = m;
    mr[bg * 2 + 1] = rsqrtf(var + 1e-6f);
  }
}

// ---------------- groupnorm apply + transpose -> hT[b][w][c] bf16 ----------------
__global__ __launch_bounds__(256) void gn_apply(
    const float* __restrict__ x, const float* __restrict__ mr,
    const float* __restrict__ gamma, const float* __restrict__ beta,
    u16* __restrict__ hT) {
  const int b = blockIdx.x >> 6;           // 8 batches
  const int w0 = (blockIdx.x & 63) * 32;   // 64 w-tiles of 32
  __shared__ u16 tile[CDIM][33];
  const float* xb = x + (size_t)b * CDIM * WDIM;
  const int c_sub = threadIdx.x >> 5;      // 0..7
  const int w_l = threadIdx.x & 31;
  for (int c0 = 0; c0 < CDIM; c0 += 8) {
    int c = c0 + c_sub;
    int g = c >> 4;
    float m = mr[(b * NGRP + g) * 2];
    float r = mr[(b * NGRP + g) * 2 + 1];
    float v = xb[(size_t)c * WDIM + w0 + w_l];
    float hn = (v - m) * r * gamma[c] + beta[c];
    tile[c][w_l] = f2bf(hn);
  }
  __syncthreads();
  #pragma unroll 4
  for (int i = 0; i < 32; i++) {
    size_t base = ((size_t)b * WDIM + w0 + i) * CDIM;
    hT[base + threadIdx.x] = tile[threadIdx.x][i];
    hT[base + 256 + threadIdx.x] = tile[256 + threadIdx.x][i];
  }
}

// ---------------- big TN GEMM: C[m][n] = sum_k A[m][k]*B[n][k] ----------------
// BM=256, BN=128, BK=64. 512 threads = 8 waves (4x2), wave tile 64x64.
// Ring-3 LDS (144KB), prefetch 2 K-tiles ahead, counted vmcnt(6),
// 2 phases per K-tile (ks=0/1), each {stage-issue | 8 ds_read | 16 MFMA},
// 2 barriers per K-tile, setprio around MFMA.
// XOR chunk-swizzle (slot ^= row&7) on BOTH pre-swizzled global staging
// source and ds_read address (LDS linear for gld_lds).
// BIAS_MODE: 0 none, 1 bias[n], 2 bias[m], 3 split-n (bq/bk at n<512/>=512).
template <int BIAS_MODE, int RESID, int SCALE, typename OutT>
__global__ __launch_bounds__(512, 1) void gemm_tn(
    const u16* __restrict__ A, const u16* __restrict__ B,
    OutT* __restrict__ Cp, const float* __restrict__ bias,
    const float* __restrict__ bias2, const float* __restrict__ resid,
    float scale, int K, int N, int lda, int ldb,
    long sAb, long sBb, long sCb) {
  extern __shared__ char smem[];           // 3 * (32KB A + 16KB B) = 147456
  const int tid = threadIdx.x;
  const int wave = tid >> 6, lane = tid & 63;
  const int wr = wave >> 1, wc = wave & 1;   // 4 x 2 wave grid, tile 64x64
  const int fr = lane & 15, kg = lane >> 4;  // frag row, k-group
  const size_t zc = (size_t)blockIdx.z * sCb;
  const u16* Ab = A + (size_t)blockIdx.z * sAb + (size_t)blockIdx.x * 256 * lda;
  const u16* Bb = B + (size_t)blockIdx.z * sBb + (size_t)blockIdx.y * 128 * ldb;

  f32x4 acc[4][4] = {};

  auto stageA = [&](int buf, int tk) {
    u16* As = (u16*)(smem + buf * 49152);
    const u16* Ag = Ab + tk * 64;
    #pragma unroll
    for (int j = 0; j < 4; ++j) {          // A: 256x64 = 2048 16B chunks
      int pc = j * 512 + tid;
      int row = pc >> 3;
      int ls = (pc & 7) ^ (row & 7);       // pre-swizzled source slot
      gld_lds16(Ag + (size_t)row * lda + ls * 8, As + pc * 8);
    }
  };
  auto stageB = [&](int buf, int tk) {
    u16* Bs = (u16*)(smem + buf * 49152 + 32768);
    const u16* Bg = Bb + tk * 64;
    #pragma unroll
    for (int j = 0; j < 2; ++j) {          // B: 128x64 = 1024 chunks
      int pc = j * 512 + tid;
      int row = pc >> 3;
      int ls = (pc & 7) ^ (row & 7);
      gld_lds16(Bg + (size_t)row * ldb + ls * 8, Bs + pc * 8);
    }
  };

  const int nt = K >> 6;                   // K-tiles of 64 (>= 8 here)
  stageA(0, 0); stageB(0, 0);
  stageA(1, 1); stageB(1, 1);
  asm volatile("s_waitcnt vmcnt(6)" ::: "memory");   // tile 0 landed (own)
  __builtin_amdgcn_s_barrier();                      // all waves' tile 0 in

  for (int t = 0; t < nt; ++t) {
    const int cur = t % 3;
    const char* As = smem + cur * 49152;
    const char* Bs = As + 32768;

    // ---- phase 0 (ks = 0) ----
    if (t + 2 < nt) stageA((t + 2) % 3, t + 2);      // 4 loads
    bf16x8 a0[4], b0[4];
    #pragma unroll
    for (int mi = 0; mi < 4; ++mi) {
      int row = wr * 64 + mi * 16 + fr;
      a0[mi] = *(const bf16x8*)(As + row * 128 + ((kg ^ (row & 7)) << 4));
    }
    #pragma unroll
    for (int ni = 0; ni < 4; ++ni) {
      int row = wc * 64 + ni * 16 + fr;
      b0[ni] = *(const bf16x8*)(Bs + row * 128 + ((kg ^ (row & 7)) << 4));
    }
    __builtin_amdgcn_sched_barrier(0);
    __builtin_amdgcn_s_barrier();                    // phase alignment
    __builtin_amdgcn_s_setprio(1);
    #pragma unroll
    for (int mi = 0; mi < 4; ++mi)
      #pragma unroll
      for (int ni = 0; ni < 4; ++ni)
        acc[mi][ni] = __builtin_amdgcn_mfma_f32_16x16x32_bf16(
            a0[mi], b0[ni], acc[mi][ni], 0, 0, 0);
    __builtin_amdgcn_s_setprio(0);

    // ---- phase 1 (ks = 1) ----
    if (t + 2 < nt) stageB((t + 2) % 3, t + 2);      // 2 loads
    bf16x8 a1[4], b1[4];
    #pragma unroll
    for (int mi = 0; mi < 4; ++mi) {
      int row = wr * 64 + mi * 16 + fr;
      a1[mi] = *(const bf16x8*)(As + row * 128 + (((4 + kg) ^ (row & 7)) << 4));
    }
    #pragma unroll
    for (int ni = 0; ni < 4; ++ni) {
      int row = wc * 64 + ni * 16 + fr;
      b1[ni] = *(const bf16x8*)(Bs + row * 128 + (((4 + kg) ^ (row & 7)) << 4));
    }
    __builtin_amdgcn_sched_barrier(0);
    if (t + 1 < nt) {
      // own lgkm drained (so post-barrier staging can't race our reads);
      // tile t+1 landed (vmcnt<=6), tile t+2's 6 loads stay in flight.
      if (t + 2 < nt)
        asm volatile("s_waitcnt vmcnt(6) lgkmcnt(0)" ::: "memory");
      else
        asm volatile("s_waitcnt vmcnt(0) lgkmcnt(0)" ::: "memory");
      __builtin_amdgcn_s_barrier();
    }
    __builtin_amdgcn_s_setprio(1);
    #pragma unroll
    for (int mi = 0; mi < 4; ++mi)
      #pragma unroll
      for (int ni = 0; ni < 4; ++ni)
        acc[mi][ni] = __builtin_amdgcn_mfma_f32_16x16x32_bf16(
            a1[mi], b1[ni], acc[mi][ni], 0, 0, 0);
    __builtin_amdgcn_s_setprio(0);
  }

  const int row0 = blockIdx.x * 256 + wr * 64 + (lane >> 4) * 4;
  const int coln = blockIdx.y * 128 + wc * 64 + fr;
  #pragma unroll
  for (int mi = 0; mi < 4; ++mi) {
    #pragma unroll
    for (int ni = 0; ni < 4; ++ni) {
      int n = coln + ni * 16;
      float badd = 0.0f;
      if (BIAS_MODE == 1) badd = bias[n];
      if (BIAS_MODE == 3) badd = (n < 512) ? bias[n] : bias2[n - 512];
      #pragma unroll
      for (int j = 0; j < 4; ++j) {
        int m = row0 + mi * 16 + j;
        float v = acc[mi][ni][j];
        if (BIAS_MODE == 2) v += bias[m]; else v += badd;
        if (SCALE) v *= scale;
        size_t idx = zc + (size_t)m * N + n;
        if (RESID) v += resid[idx];
        if constexpr (sizeof(OutT) == 2) {
          Cp[idx] = (OutT)f2bf(v);
        } else {
          Cp[idx] = v;
        }
      }
    }
  }
}

// ---------------- row softmax in place over bf16 scores ----------------
__global__ __launch_bounds__(256) void softmax_rows(u16* __restrict__ sc) {
  const size_t base = (size_t)blockIdx.x * WDIM;
  const int tid = threadIdx.x;
  bf16x8 raw = *(const bf16x8*)(sc + base + tid * 8);
  float v[8];
  float mx = -1e30f;
  #pragma unroll
  for (int j = 0; j < 8; j++) {
    v[j] = bf2f((u16)raw[j]);
    mx = fmaxf(mx, v[j]);
  }
  for (int off = 32; off; off >>= 1) mx = fmaxf(mx, __shfl_xor(mx, off, 64));
  __shared__ float smx[4], ssum[4];
  if ((tid & 63) == 0) smx[tid >> 6] = mx;
  __syncthreads();
  mx = fmaxf(fmaxf(smx[0], smx[1]), fmaxf(smx[2], smx[3]));
  float sum = 0.f;
  #pragma unroll
  for (int j = 0; j < 8; j++) {
    v[j] = __expf(v[j] - mx);
    sum += v[j];
  }
  for (int off = 32; off; off >>= 1) sum += __shfl_xor(sum, off, 64);
  if ((tid & 63) == 0) ssum[tid >> 6] = sum;
  __syncthreads();
  float r = 1.0f / (ssum[0] + ssum[1] + ssum[2] + ssum[3]);
  bf16x8 outv;
  #pragma unroll
  for (int j = 0; j < 8; j++) outv[j] = (short)f2bf(v[j] * r);
  *(bf16x8*)(sc + base + tid * 8) = outv;
}

extern "C" void kernel_launch(void* const* d_in, const int* in_sizes, int n_in,
                              void* d_out, int out_size, void* d_ws,
                              size_t ws_size, hipStream_t stream) {
  const float* x     = (const float*)d_in[0];
  const float* gamma = (const float*)d_in[1];
  const float* beta  = (const float*)d_in[2];
  const float* wq    = (const float*)d_in[3];
  const float* bq    = (const float*)d_in[4];
  const float* wk    = (const float*)d_in[5];
  const float* bk    = (const float*)d_in[6];
  const float* wv    = (const float*)d_in[7];
  const float* bv    = (const float*)d_in[8];
  const float* wp    = (const float*)d_in[9];
  const float* bp    = (const float*)d_in[10];
  float* out = (float*)d_out;

  char* ws = (char*)d_ws;
  u16* wq_bf = (u16*)ws;                    // wq,wk contiguous => combined B
  u16* wv_bf = wq_bf + 524288;
  u16* wp_bf = wv_bf + 262144;
  float* mr = (float*)(ws + 4 * 524288);    // 512 floats (mean,rstd)
  u16* hT = (u16*)(ws + 4 * 524288 + 4096); // 8*2048*512
  u16* qk = hT + 8388608;                   // 8*2048*1024 (q | k)
  u16* vB = qk + 16777216;                  // 8*512*2048
  u16* oT = vB + 8388608;                   // 8*2048*512
  u16* sc = oT + 8388608;                   // 8*2048*2048

  const long sWC = (long)WDIM * CDIM;       // 1048576
  const long sCW = (long)CDIM * WDIM;
  const long sW1024 = (long)WDIM * 1024;
  const long sWW = (long)WDIM * WDIM;       // 4194304

  const int SMEM = 147456;
  (void)hipFuncSetAttribute((const void*)&gemm_tn<3, 0, 0, u16>,
      hipFuncAttributeMaxDynamicSharedMemorySize, SMEM);
  (void)hipFuncSetAttribute((const void*)&gemm_tn<2, 0, 0, u16>,
      hipFuncAttributeMaxDynamicSharedMemorySize, SMEM);
  (void)hipFuncSetAttribute((const void*)&gemm_tn<0, 0, 1, u16>,
      hipFuncAttributeMaxDynamicSharedMemorySize, SMEM);
  (void)hipFuncSetAttribute((const void*)&gemm_tn<0, 0, 0, u16>,
      hipFuncAttributeMaxDynamicSharedMemorySize, SMEM);
  (void)hipFuncSetAttribute((const void*)&gemm_tn<2, 1, 0, float>,
      hipFuncAttributeMaxDynamicSharedMemorySize, SMEM);

  cvt_weights<<<1024, 256, 0, stream>>>(wq, wk, wv, wp, wq_bf);
  gn_stats<<<BDIM * NGRP, 256, 0, stream>>>(x, mr);
  gn_apply<<<BDIM * 64, 256, 0, stream>>>(x, mr, gamma, beta, hT);

  const float scale = 0.04419417382415922f;  // 512^-0.5

  // qk[b][w][0:512]=h.Wq^T+bq ; [512:1024]=h.Wk^T+bk
  gemm_tn<3, 0, 0, u16><<<dim3(8, 8, 8), 512, SMEM, stream>>>(
      hT, wq_bf, qk, bq, bk, nullptr, 1.f, 512, 1024, 512, 512,
      sWC, 0, sW1024);
  // v[b][c][w] = Wv . h + bv
  gemm_tn<2, 0, 0, u16><<<dim3(2, 16, 8), 512, SMEM, stream>>>(
      wv_bf, hT, vB, bv, nullptr, nullptr, 1.f, 512, 2048, 512, 512,
      0, sWC, sCW);
  // scores[b][i][j] = (q . k) * c^-0.5
  gemm_tn<0, 0, 1, u16><<<dim3(8, 16, 8), 512, SMEM, stream>>>(
      qk, qk + 512, sc, nullptr, nullptr, nullptr, scale, 512, 2048,
      1024, 1024, sW1024, sW1024, sWW);
  // softmax rows
  softmax_rows<<<BDIM * WDIM, 256, 0, stream>>>(sc);
  // oT[b][i][c] = att . v^T
  gemm_tn<0, 0, 0, u16><<<dim3(8, 4, 8), 512, SMEM, stream>>>(
      sc, vB, oT, nullptr, nullptr, nullptr, 1.f, 2048, 512, 2048, 2048,
      sWW, sCW, sWC);
  // out[b][c][i] = wp . o + bp + x
  gemm_tn<2, 1, 0, float><<<dim3(2, 16, 8), 512, SMEM, stream>>>(
      wp_bf, oT, out, bp, nullptr, x, 1.f, 512, 2048, 512, 512,
      0, sWC, sCW);
}